// Round 1
// baseline (47.891 us; speedup 1.0000x reference)
//
#include <hip/hip_runtime.h>

#define EPS 1e-6f
constexpr int B = 16, C = 26, H = 256, W = 256;
constexpr int CHW  = C * H * W;   // 1,703,936
constexpr int CHW4 = CHW / 4;     // 425,984 float4s per batch
constexpr int HW2  = 2 * H * W;   // 131,072 (hw_pred flat dim per batch)
constexpr int P = 20, K = 2, E = 26;
constexpr int NBPB = 128;         // focal blocks per batch

__device__ inline float waveReduceSum(float v) {
#pragma unroll
  for (int o = 32; o > 0; o >>= 1) v += __shfl_down(v, o, 64);
  return v;
}

// ---------------- Kernel 1: focal-loss partial reduction ----------------
// grid (NBPB, B) x 256 threads. Each block writes {pl, nl, num_pos, 0} to ws.
__global__ __launch_bounds__(256) void focal_partial_kernel(
    const float4* __restrict__ pred, const float4* __restrict__ gt,
    float* __restrict__ partials) {
  const int b = blockIdx.y;
  const float4* pp = pred + (size_t)b * CHW4;
  const float4* gg = gt + (size_t)b * CHW4;
  float pl = 0.f, nl = 0.f, npos = 0.f;
  for (int i = blockIdx.x * 256 + threadIdx.x; i < CHW4; i += NBPB * 256) {
    float4 x4 = pp[i];
    float4 g4 = gg[i];
    float xs[4] = {x4.x, x4.y, x4.z, x4.w};
    float gs[4] = {g4.x, g4.y, g4.z, g4.w};
#pragma unroll
    for (int j = 0; j < 4; ++j) {
      float x = xs[j], g = gs[j];
      float p = 1.f / (1.f + __expf(-x));
      if (g == 1.0f) {
        float omp = 1.f - p;
        pl += __logf(p + EPS) * omp * omp;
        npos += 1.f;
      } else if (g < 1.0f) {
        float og = 1.f - g;
        float og2 = og * og;
        nl += __logf(1.f - p + EPS) * p * p * (og2 * og2);
      }
    }
  }
  pl = waveReduceSum(pl);
  nl = waveReduceSum(nl);
  npos = waveReduceSum(npos);
  __shared__ float s[3][4];
  int wave = threadIdx.x >> 6, lane = threadIdx.x & 63;
  if (lane == 0) { s[0][wave] = pl; s[1][wave] = nl; s[2][wave] = npos; }
  __syncthreads();
  if (threadIdx.x == 0) {
    float* o = partials + ((size_t)b * NBPB + blockIdx.x) * 4;
    o[0] = s[0][0] + s[0][1] + s[0][2] + s[0][3];
    o[1] = s[1][0] + s[1][1] + s[1][2] + s[1][3];
    o[2] = s[2][0] + s[2][1] + s[2][2] + s[2][3];
    o[3] = 0.f;
  }
}

// ---------------- Kernel 2: hw reg-L1 loss (tiny gather) ----------------
// grid (B) x 64 threads; threads 0..39 handle (p,k).
__global__ __launch_bounds__(64) void hw_kernel(
    const float* __restrict__ pred, const float* __restrict__ gt,
    float* __restrict__ res) {
  int b = blockIdx.x, t = threadIdx.x;
  float contrib = 0.f;
  bool wv = false;
  if (t < P * K) {
    const float* g3 = gt + ((size_t)(b * P * K + t)) * 3;
    float val = g3[0];
    int idx = (int)g3[1];
    wv = g3[2] > 0.f;
    float gv = pred[(size_t)b * HW2 + idx];
    contrib = wv ? fabsf(gv - val) : 0.f;
  }
  unsigned long long m = __ballot(wv);
  float l1 = waveReduceSum(contrib);
  if (t == 0) {
    // person p occupies bits 2p, 2p+1; n_people = # persons with any w
    unsigned long long mm = (m | (m >> 1)) & 0x5555555555ULL;
    res[b * 2 + 0] = l1;
    res[b * 2 + 1] = (float)__popcll(mm);
  }
}

// ---------------- Kernel 3: bu emo-focal-tag loss (tiny gather) ----------------
// grid (P, B) x 64 threads; threads 0..25 handle e.
__global__ __launch_bounds__(64) void bu_kernel(
    const float* __restrict__ pred, const float* __restrict__ gt,
    float* __restrict__ pp_out, float* __restrict__ pv_out) {
  int p = blockIdx.x, b = blockIdx.y, e = threadIdx.x;
  float pl = 0.f, nl = 0.f, npos = 0.f;
  bool mv = false;
  if (e < E) {
    const float* g3 = gt + ((size_t)((b * P + p) * E + e)) * 3;
    float val = g3[0];
    int idx = (int)g3[1];
    mv = g3[2] > 0.f;
    float x = pred[(size_t)b * CHW + idx];
    float gv = 1.f / (1.f + __expf(-x));
    if (mv) {
      if (val == 1.0f) {
        float o = 1.f - gv;
        pl = __logf(gv + EPS) * o * o;
        npos = 1.f;
      } else {  // val < 1 && m
        nl = __logf(1.f - gv + EPS) * gv * gv;
      }
    }
  }
  unsigned long long m = __ballot(mv);
  pl = waveReduceSum(pl);
  nl = waveReduceSum(nl);
  npos = waveReduceSum(npos);
  if (e == 0) {
    float per_person = (npos == 0.f) ? -nl : -(pl + nl);
    float pv = (m != 0ULL) ? 1.f : 0.f;
    pp_out[b * P + p] = per_person * pv;
    pv_out[b * P + p] = pv;
  }
}

// ---------------- Kernel 4: finalize all 48 outputs ----------------
// grid (B) x 128 threads (NBPB partials each).
__global__ __launch_bounds__(128) void finalize_kernel(
    const float* __restrict__ partials, const float* __restrict__ hw_res,
    const float* __restrict__ bu_pp, const float* __restrict__ bu_pv,
    float* __restrict__ out) {
  int b = blockIdx.x, t = threadIdx.x;
  const float* pb = partials + (size_t)b * NBPB * 4;
  float pl = pb[t * 4 + 0], nl = pb[t * 4 + 1], npos = pb[t * 4 + 2];
  pl = waveReduceSum(pl);
  nl = waveReduceSum(nl);
  npos = waveReduceSum(npos);
  __shared__ float s[3][2];
  int wave = t >> 6, lane = t & 63;
  if (lane == 0) { s[0][wave] = pl; s[1][wave] = nl; s[2][wave] = npos; }
  __syncthreads();
  if (t == 0) {
    float PL = s[0][0] + s[0][1];
    float NL = s[1][0] + s[1][1];
    float NP = s[2][0] + s[2][1];
    float hm = (NP > 0.f) ? (-(PL + NL) / fmaxf(NP, 1.f)) : -NL;
    out[b] = hm * 1.0f;  // HM_FACTOR
    float l1 = hw_res[b * 2 + 0], npe = hw_res[b * 2 + 1];
    out[16 + b] = ((npe > 0.f) ? l1 / fmaxf(npe, 1.f) : 0.f) * 0.1f;  // HW_FACTOR
    float spp = 0.f, spv = 0.f;
    for (int i = 0; i < P; ++i) {
      spp += bu_pp[b * P + i];
      spv += bu_pv[b * P + i];
    }
    out[32 + b] = (spp / fmaxf(spv, 1.f)) * 1.0f;  // BU_FACTOR
  }
}

extern "C" void kernel_launch(void* const* d_in, const int* in_sizes, int n_in,
                              void* d_out, int out_size, void* d_ws, size_t ws_size,
                              hipStream_t stream) {
  const float* hm_pred = (const float*)d_in[0];
  const float* hm_gt   = (const float*)d_in[1];
  const float* hw_pred = (const float*)d_in[2];
  const float* hw_gt   = (const float*)d_in[3];
  const float* bu_pred = (const float*)d_in[4];
  const float* bu_gt   = (const float*)d_in[5];
  float* out = (float*)d_out;

  float* ws = (float*)d_ws;
  float* partials = ws;                       // B*NBPB*4 = 8192 floats
  float* hw_res   = partials + B * NBPB * 4;  // 32 floats
  float* bu_pp    = hw_res + B * 2;           // 320 floats
  float* bu_pv    = bu_pp + B * P;            // 320 floats

  hipLaunchKernelGGL(focal_partial_kernel, dim3(NBPB, B), dim3(256), 0, stream,
                     (const float4*)hm_pred, (const float4*)hm_gt, partials);
  hipLaunchKernelGGL(hw_kernel, dim3(B), dim3(64), 0, stream,
                     hw_pred, hw_gt, hw_res);
  hipLaunchKernelGGL(bu_kernel, dim3(P, B), dim3(64), 0, stream,
                     bu_pred, bu_gt, bu_pp, bu_pv);
  hipLaunchKernelGGL(finalize_kernel, dim3(B), dim3(128), 0, stream,
                     partials, hw_res, bu_pp, bu_pv, out);
}